// Round 2
// baseline (1362.607 us; speedup 1.0000x reference)
//
#include <hip/hip_runtime.h>

#define EE 512
#define SS 128
#define BB 4
#define NH 8
#define HD 64
#define FFD 2048
#define NL 4

struct Ptr4 {
    const float* w0; const float* w1; const float* w2; const float* w3;
    float* c0; float* c1; float* c2; float* c3;
};

// ---------------------------------------------------------------------------
// Shared GEMM tile body: C[M,N] = A[M,K] @ B[N,K]^T, fp32, tile 64x64, BK=16,
// 256 threads, 4x4 micro-tile. flags bit0=+bias[col], bit1=relu.
// resid != nullptr -> += resid[row,col].
// ---------------------------------------------------------------------------
__device__ __forceinline__ void gemm_tile(
    const float* __restrict__ A, const float* __restrict__ Bm,
    float* __restrict__ C, const float* __restrict__ bias,
    const float* __restrict__ resid, int M, int N, int K, int flags)
{
    __shared__ float As[16][64];
    __shared__ float Bs[16][64];
    const int t  = threadIdx.x;
    const int tx = t & 15, ty = t >> 4;
    const int rowBase = blockIdx.y * 64, colBase = blockIdx.x * 64;
    const int rA = t >> 2;          // 0..63
    const int c4 = (t & 3) * 4;     // 0,4,8,12
    const bool aok = (rowBase + rA) < M;   // N is always a multiple of 64 here
    const float* Aload = A + (size_t)(rowBase + rA) * K + c4;
    const float* Bload = Bm + (size_t)(colBase + rA) * K + c4;

    float acc[4][4] = {};
    for (int k0 = 0; k0 < K; k0 += 16) {
        float4 av;
        if (aok) av = *(const float4*)(Aload + k0);
        else     av = make_float4(0.f, 0.f, 0.f, 0.f);
        float4 bv = *(const float4*)(Bload + k0);
        __syncthreads();
        As[c4 + 0][rA] = av.x; As[c4 + 1][rA] = av.y;
        As[c4 + 2][rA] = av.z; As[c4 + 3][rA] = av.w;
        Bs[c4 + 0][rA] = bv.x; Bs[c4 + 1][rA] = bv.y;
        Bs[c4 + 2][rA] = bv.z; Bs[c4 + 3][rA] = bv.w;
        __syncthreads();
#pragma unroll
        for (int kk = 0; kk < 16; ++kk) {
            float4 a = *(const float4*)&As[kk][ty * 4];
            float4 b = *(const float4*)&Bs[kk][tx * 4];
            acc[0][0] += a.x * b.x; acc[0][1] += a.x * b.y;
            acc[0][2] += a.x * b.z; acc[0][3] += a.x * b.w;
            acc[1][0] += a.y * b.x; acc[1][1] += a.y * b.y;
            acc[1][2] += a.y * b.z; acc[1][3] += a.y * b.w;
            acc[2][0] += a.z * b.x; acc[2][1] += a.z * b.y;
            acc[2][2] += a.z * b.z; acc[2][3] += a.z * b.w;
            acc[3][0] += a.w * b.x; acc[3][1] += a.w * b.y;
            acc[3][2] += a.w * b.z; acc[3][3] += a.w * b.w;
        }
    }
#pragma unroll
    for (int i2 = 0; i2 < 4; ++i2) {
        const int row = rowBase + ty * 4 + i2;
        if (row < M) {
#pragma unroll
            for (int j2 = 0; j2 < 4; ++j2) {
                const int col = colBase + tx * 4 + j2;
                float v = acc[i2][j2];
                if (flags & 1) v += bias[col];
                if (flags & 2) v = fmaxf(v, 0.f);
                if (resid) v += resid[(size_t)row * N + col];
                C[(size_t)row * N + col] = v;
            }
        }
    }
}

__global__ __launch_bounds__(256) void gemm_nt(
    const float* __restrict__ A, const float* __restrict__ Bm,
    float* __restrict__ C, const float* __restrict__ bias,
    const float* __restrict__ resid, int M, int N, int K, int flags)
{
    gemm_tile(A, Bm, C, bias, resid, M, N, K, flags);
}

// Batched QKVV projection: gridDim.z selects one of 4 weight/output pairs.
__global__ __launch_bounds__(256) void gemm_qkvv(
    const float* __restrict__ A, Ptr4 p, int M, int N, int K)
{
    const float* w; float* c;
    switch (blockIdx.z) {
        case 0:  w = p.w0; c = p.c0; break;
        case 1:  w = p.w1; c = p.c1; break;
        case 2:  w = p.w2; c = p.c2; break;
        default: w = p.w3; c = p.c3; break;
    }
    gemm_tile(A, w, c, nullptr, nullptr, M, N, K, 0);
}

// ---------------------------------------------------------------------------
// LayerNorm over rows of 512. One wave per row, 4 rows per 256-thread block.
// ---------------------------------------------------------------------------
__global__ __launch_bounds__(256) void ln_kernel(
    const float* __restrict__ X, const float* __restrict__ g,
    const float* __restrict__ bt, float* __restrict__ Y, int rows)
{
    const int w = threadIdx.x >> 6, lane = threadIdx.x & 63;
    const int row = blockIdx.x * 4 + w;
    if (row >= rows) return;
    const float* x = X + (size_t)row * EE;
    float4 v0 = ((const float4*)x)[lane];
    float4 v1 = ((const float4*)x)[lane + 64];
    float s  = v0.x + v0.y + v0.z + v0.w + v1.x + v1.y + v1.z + v1.w;
    float q2 = v0.x*v0.x + v0.y*v0.y + v0.z*v0.z + v0.w*v0.w
             + v1.x*v1.x + v1.y*v1.y + v1.z*v1.z + v1.w*v1.w;
#pragma unroll
    for (int o = 32; o; o >>= 1) {
        s  += __shfl_xor(s, o);
        q2 += __shfl_xor(q2, o);
    }
    const float mean = s * (1.f / EE);
    const float var  = q2 * (1.f / EE) - mean * mean;
    const float rstd = rsqrtf(var + 1e-5f);
    float4 g0 = ((const float4*)g)[lane],  g1 = ((const float4*)g)[lane + 64];
    float4 b0 = ((const float4*)bt)[lane], b1 = ((const float4*)bt)[lane + 64];
    float4 o0, o1;
    o0.x = (v0.x - mean) * rstd * g0.x + b0.x;
    o0.y = (v0.y - mean) * rstd * g0.y + b0.y;
    o0.z = (v0.z - mean) * rstd * g0.z + b0.z;
    o0.w = (v0.w - mean) * rstd * g0.w + b0.w;
    o1.x = (v1.x - mean) * rstd * g1.x + b1.x;
    o1.y = (v1.y - mean) * rstd * g1.y + b1.y;
    o1.z = (v1.z - mean) * rstd * g1.z + b1.z;
    o1.w = (v1.w - mean) * rstd * g1.w + b1.w;
    float* y = Y + (size_t)row * EE;
    ((float4*)y)[lane] = o0;
    ((float4*)y)[lane + 64] = o1;
}

// ---------------------------------------------------------------------------
// Fused attention for one (b, i) query row, all 8 heads. 256 threads.
//   score[h][j] = (q_h . (k[b,j,h]+kproj[know_adj[b,i,j],h]) + qpe[h][pos[i,j]])
//                 * 0.125 - (1-adj)*1e30
//   attn = softmax_j ; ap[h][p] = sum_{j:pos=p} attn
//   out[h][d] = sum_j attn*(sm*vs + om*vo) + sum_p ap[p]*pe_v[p][d]
// ---------------------------------------------------------------------------
__global__ __launch_bounds__(256) void attn_kernel(
    const float* __restrict__ q, const float* __restrict__ k,
    const float* __restrict__ vs, const float* __restrict__ vo,
    const float* __restrict__ kproj,
    const int* __restrict__ know_adj, const int* __restrict__ pos_mask,
    const float* __restrict__ pe_k, const float* __restrict__ pe_v,
    const int* __restrict__ adj, const int* __restrict__ s_mask,
    const int* __restrict__ o_mask, float* __restrict__ attn_sum)
{
    const int blk = blockIdx.x;
    const int b = blk >> 7;        // / SS
    const int i = blk & 127;       // % SS
    const int t = threadIdx.x;

    __shared__ float q_s[EE];
    __shared__ float sc[NH][SS];
    __shared__ float qpe[NH][11];
    __shared__ float ap[NH][11];
    __shared__ float ws_s[SS], wo_s[SS];
    __shared__ int   pos_s[SS], n_s[SS], adj_s[SS];

    // phase 0: stage q row + per-j metadata
    if (t < 128) {
        ((float4*)q_s)[t] = ((const float4*)(q + (size_t)(b * SS + i) * EE))[t];
    } else {
        const int j = t - 128;
        const size_t off = ((size_t)(b * SS + i)) * SS + j;
        n_s[j]   = know_adj[off];
        adj_s[j] = adj[off];
        ws_s[j]  = (float)s_mask[off];
        wo_s[j]  = (float)o_mask[off];
        int p = pos_mask[i * SS + j];
        pos_s[j] = p > 10 ? 10 : (p < 0 ? 0 : p);
    }
    __syncthreads();

    // phase 1: qpe[h][p] = q_h . pe_k[p];  zero ap
    if (t < NH * 11) {
        const int h = t / 11, p = t % 11;
        const float* pk = pe_k + p * HD;
        const float* qh = q_s + h * HD;
        float a = 0.f;
#pragma unroll
        for (int d = 0; d < HD; ++d) a += qh[d] * pk[d];
        qpe[h][p] = a;
        ap[h][p] = 0.f;
    }
    __syncthreads();

    // phase 2: scores. thread -> (j = t>>1, half s = t&1 -> 4 heads)
    {
        const int j = t >> 1, s = t & 1;
        const int n = n_s[j];
        const float4* kp = (const float4*)(kproj + (size_t)n * EE + s * 256);
        const float4* kr = (const float4*)(k + (size_t)(b * SS + j) * EE + s * 256);
        const float amask = adj_s[j] ? 0.f : 1e30f;
        const int p = pos_s[j];
#pragma unroll
        for (int h4 = 0; h4 < 4; ++h4) {
            const int h = s * 4 + h4;
            const float* qh = q_s + h * HD;
            float acc = 0.f;
#pragma unroll
            for (int dv = 0; dv < 16; ++dv) {
                float4 kv = kr[h4 * 16 + dv];
                float4 pv = kp[h4 * 16 + dv];
                acc += qh[dv * 4 + 0] * (kv.x + pv.x);
                acc += qh[dv * 4 + 1] * (kv.y + pv.y);
                acc += qh[dv * 4 + 2] * (kv.z + pv.z);
                acc += qh[dv * 4 + 3] * (kv.w + pv.w);
            }
            sc[h][j] = (acc + qpe[h][p]) * 0.125f - amask;
        }
    }
    __syncthreads();

    // phase 3: softmax per head (wave w -> heads 2w, 2w+1) + ap accumulation
    {
        const int w = t >> 6, lane = t & 63;
#pragma unroll
        for (int hh = 0; hh < 2; ++hh) {
            const int h = w * 2 + hh;
            float v0 = sc[h][lane], v1 = sc[h][lane + 64];
            float m = fmaxf(v0, v1);
#pragma unroll
            for (int o = 32; o; o >>= 1) m = fmaxf(m, __shfl_xor(m, o));
            float e0 = __expf(v0 - m), e1 = __expf(v1 - m);
            float ssum = e0 + e1;
#pragma unroll
            for (int o = 32; o; o >>= 1) ssum += __shfl_xor(ssum, o);
            const float inv = 1.f / ssum;
            e0 *= inv; e1 *= inv;
            sc[h][lane] = e0; sc[h][lane + 64] = e1;
            atomicAdd(&ap[h][pos_s[lane]], e0);
            atomicAdd(&ap[h][pos_s[lane + 64]], e1);
        }
    }
    __syncthreads();

    // phase 4: out[h][d]; thread t -> (h0 = t>>6, d = t&63) and h0+4
    {
        const int h0 = t >> 6, d = t & 63;
        const int h1 = h0 + 4;
        float acc0 = 0.f, acc1 = 0.f;
        const float* vsb = vs + (size_t)b * SS * EE;
        const float* vob = vo + (size_t)b * SS * EE;
        for (int j = 0; j < SS; ++j) {
            const float a0 = sc[h0][j], a1 = sc[h1][j];
            const float wsj = ws_s[j], woj = wo_s[j];
            const size_t o0 = (size_t)j * EE + h0 * HD + d;
            const size_t o1 = (size_t)j * EE + h1 * HD + d;
            acc0 += a0 * (wsj * vsb[o0] + woj * vob[o0]);
            acc1 += a1 * (wsj * vsb[o1] + woj * vob[o1]);
        }
#pragma unroll
        for (int p = 0; p < 11; ++p) {
            acc0 += ap[h0][p] * pe_v[p * HD + d];
            acc1 += ap[h1][p] * pe_v[p * HD + d];
        }
        const size_t ob = (size_t)(b * SS + i) * EE;
        attn_sum[ob + h0 * HD + d] = acc0;
        attn_sum[ob + h1 * HD + d] = acc1;
    }
}

// ---------------------------------------------------------------------------
extern "C" void kernel_launch(void* const* d_in, const int* in_sizes, int n_in,
                              void* d_out, int out_size, void* d_ws, size_t ws_size,
                              hipStream_t stream)
{
    const float* x         = (const float*)d_in[0];
    const int*   adj       = (const int*)d_in[1];
    const int*   s_mask    = (const int*)d_in[2];
    const int*   o_mask    = (const int*)d_in[3];
    const float* knowledge = (const float*)d_in[4];
    const int*   know_adj  = (const int*)d_in[5];
    const int*   pos_mask  = (const int*)d_in[6];
    const float* pe_k      = (const float*)d_in[7];
    const float* pe_v      = (const float*)d_in[8];
    const float* Wq        = (const float*)d_in[9];
    const float* Wk        = (const float*)d_in[10];
    const float* Wvs       = (const float*)d_in[11];
    const float* Wvo       = (const float*)d_in[12];
    const float* Wo        = (const float*)d_in[13];
    const float* Wkn       = (const float*)d_in[14];
    const float* ln1_g     = (const float*)d_in[15];
    const float* ln1_b     = (const float*)d_in[16];
    const float* w1        = (const float*)d_in[17];
    const float* b1        = (const float*)d_in[18];
    const float* w2        = (const float*)d_in[19];
    const float* b2        = (const float*)d_in[20];
    const float* ln2_g     = (const float*)d_in[21];
    const float* ln2_b     = (const float*)d_in[22];

    const int NTOK = BB * SS;              // 512
    const size_t NTE = (size_t)NTOK * EE;  // 262144

    float* ws    = (float*)d_ws;
    float* h     = ws;                  // [512,512]
    float* qb    = ws + 1 * NTE;
    float* kb    = ws + 2 * NTE;
    float* vsb   = ws + 3 * NTE;
    float* vob   = ws + 4 * NTE;
    float* kproj = ws + 5 * NTE;        // [1000,512]
    float* asum  = kproj + 1000 * EE;
    float* xt    = asum + NTE;
    float* ffn   = xt + NTE;            // [512,2048]

    hipMemcpyAsync(h, x, NTE * sizeof(float), hipMemcpyDeviceToDevice, stream);

    const dim3 blk(256);
    for (int l = 0; l < NL; ++l) {
        const size_t wo_off = (size_t)l * EE * EE;
        Ptr4 p;
        p.w0 = Wq + wo_off; p.w1 = Wk + wo_off; p.w2 = Wvs + wo_off; p.w3 = Wvo + wo_off;
        p.c0 = qb; p.c1 = kb; p.c2 = vsb; p.c3 = vob;
        gemm_qkvv<<<dim3(8, 8, 4), blk, 0, stream>>>(h, p, NTOK, EE, EE);
        gemm_nt<<<dim3(8, 16), blk, 0, stream>>>(knowledge, Wkn + wo_off, kproj, nullptr, nullptr, 1000, EE, EE, 0);
        attn_kernel<<<dim3(NTOK), blk, 0, stream>>>(qb, kb, vsb, vob, kproj,
                                                    know_adj, pos_mask, pe_k, pe_v,
                                                    adj, s_mask, o_mask, asum);
        gemm_nt<<<dim3(8, 8), blk, 0, stream>>>(asum, Wo + wo_off, xt, nullptr, h, NTOK, EE, EE, 0);
        ln_kernel<<<dim3(128), blk, 0, stream>>>(xt, ln1_g + l * EE, ln1_b + l * EE, h, NTOK);
        gemm_nt<<<dim3(32, 8), blk, 0, stream>>>(h, w1 + (size_t)l * FFD * EE, ffn,
                                                 b1 + (size_t)l * FFD, nullptr, NTOK, FFD, EE, 3);
        gemm_nt<<<dim3(8, 8), blk, 0, stream>>>(ffn, w2 + (size_t)l * EE * FFD, xt,
                                                b2 + (size_t)l * EE, h, NTOK, EE, FFD, 1);
        ln_kernel<<<dim3(128), blk, 0, stream>>>(xt, ln2_g + l * EE, ln2_b + l * EE, h, NTOK);
    }

    hipMemcpyAsync(d_out, h, NTE * sizeof(float), hipMemcpyDeviceToDevice, stream);
}

// Round 3
// 746.324 us; speedup vs baseline: 1.8258x; 1.8258x over previous
//
#include <hip/hip_runtime.h>

#define EE 512
#define SS 128
#define BB 4
#define NH 8
#define HD 64
#define FFD 2048
#define NL 4
#define LDQ 2048   // qkvv concat leading dim

typedef short bf16x8 __attribute__((ext_vector_type(8)));
typedef float f32x4 __attribute__((ext_vector_type(4)));

__device__ __forceinline__ ushort f2bf(float f) {
    uint u = __float_as_uint(f);
    return (ushort)((u + 0x7fffu + ((u >> 16) & 1u)) >> 16);
}
__device__ __forceinline__ float bflo(uint u) { return __uint_as_float(u << 16); }
__device__ __forceinline__ float bfhi(uint u) { return __uint_as_float(u & 0xffff0000u); }
__device__ __forceinline__ float bfu(ushort u) { return __uint_as_float((uint)u << 16); }

// ---------------------------------------------------------------------------
// bf16 MFMA GEMM: C[M,N] = A[M,K] @ B[N,K]^T. A,B bf16 row-major (lda=ldb=K).
// Tile BM x 64, BK=64, 256 threads (4 waves). 16x16x32 MFMA.
// LDS XOR-swizzled (G4): ushort idx = row*64 + ((c16*8) ^ ((row&7)<<3)).
// flags: bit0 = +bias[col] (f32), bit1 = relu. resid f32 optional.
// Outputs: Cf (f32) and/or Cb (bf16), ldc = N.
// Two jobs per launch (block ranges) to batch small GEMMs.
// ---------------------------------------------------------------------------
struct GemmJob {
    const ushort* A; const ushort* B;
    float* Cf; ushort* Cb;
    const float* bias; const float* resid;
    int M, N, K, flags, nbx, base;
};

template<int BM>
__global__ __launch_bounds__(256) void gemm_bf16(GemmJob j0, GemmJob j1, int njobs)
{
    __shared__ ushort As[BM * 64];
    __shared__ ushort Bs[64 * 64];
    GemmJob j = (njobs > 1 && (int)blockIdx.x >= j1.base) ? j1 : j0;
    const int bid = (int)blockIdx.x - j.base;
    const int by = bid / j.nbx, bx = bid % j.nbx;
    const int rowBase = by * BM, colBase = bx * 64;
    const int t = threadIdx.x, lane = t & 63, wid = t >> 6;
    constexpr int WAVES_M = BM / 32;        // 2 (BM=64) or 1 (BM=32)
    constexpr int WAVES_N = 4 / WAVES_M;    // 2 or 4
    constexpr int N_REP   = 4 / WAVES_N;    // 2 or 1
    constexpr int A_SEG   = BM / 32;        // 16B segments per thread for A
    const int wr = wid / WAVES_N, wc = wid % WAVES_N;
    const int srow = t >> 3;                // 0..31
    const int sc16 = t & 7;                 // 16B column index
    const int K = j.K, M = j.M, N = j.N;

    f32x4 acc[2][N_REP];
#pragma unroll
    for (int m = 0; m < 2; ++m)
#pragma unroll
        for (int n = 0; n < N_REP; ++n)
#pragma unroll
            for (int r = 0; r < 4; ++r) acc[m][n][r] = 0.f;

    for (int k0 = 0; k0 < K; k0 += 64) {
        uint4 ar[A_SEG], br[2];
#pragma unroll
        for (int s = 0; s < A_SEG; ++s) {
            int row = srow + s * 32;
            int gr = rowBase + row; gr = gr < M ? gr : M - 1;
            ar[s] = *(const uint4*)(j.A + (size_t)gr * K + k0 + sc16 * 8);
        }
#pragma unroll
        for (int s = 0; s < 2; ++s) {
            int row = srow + s * 32;
            br[s] = *(const uint4*)(j.B + (size_t)(colBase + row) * K + k0 + sc16 * 8);
        }
        __syncthreads();
#pragma unroll
        for (int s = 0; s < A_SEG; ++s) {
            int row = srow + s * 32;
            *(uint4*)(As + row * 64 + ((sc16 * 8) ^ ((row & 7) << 3))) = ar[s];
        }
#pragma unroll
        for (int s = 0; s < 2; ++s) {
            int row = srow + s * 32;
            *(uint4*)(Bs + row * 64 + ((sc16 * 8) ^ ((row & 7) << 3))) = br[s];
        }
        __syncthreads();
#pragma unroll
        for (int kc = 0; kc < 2; ++kc) {
            const int c16 = kc * 4 + (lane >> 4);
            bf16x8 af[2], bfr[N_REP];
#pragma unroll
            for (int m = 0; m < 2; ++m) {
                int row = wr * 32 + m * 16 + (lane & 15);
                af[m] = *(const bf16x8*)(As + row * 64 + ((c16 * 8) ^ ((row & 7) << 3)));
            }
#pragma unroll
            for (int n = 0; n < N_REP; ++n) {
                int row = wc * (N_REP * 16) + n * 16 + (lane & 15);
                bfr[n] = *(const bf16x8*)(Bs + row * 64 + ((c16 * 8) ^ ((row & 7) << 3)));
            }
#pragma unroll
            for (int m = 0; m < 2; ++m)
#pragma unroll
                for (int n = 0; n < N_REP; ++n)
                    acc[m][n] = __builtin_amdgcn_mfma_f32_16x16x32_bf16(
                        af[m], bfr[n], acc[m][n], 0, 0, 0);
        }
    }

    // epilogue: C/D layout col=lane&15, row=(lane>>4)*4+reg  [m89-verified]
    const int cl = lane & 15, rh = lane >> 4;
#pragma unroll
    for (int m = 0; m < 2; ++m) {
#pragma unroll
        for (int n = 0; n < N_REP; ++n) {
            const int col = colBase + wc * (N_REP * 16) + n * 16 + cl;
            const int row0 = rowBase + wr * 32 + m * 16 + rh * 4;
#pragma unroll
            for (int r = 0; r < 4; ++r) {
                const int rr = row0 + r;
                if (rr < M) {
                    float v = acc[m][n][r];
                    if (j.flags & 1) v += j.bias[col];
                    if (j.flags & 2) v = fmaxf(v, 0.f);
                    if (j.resid) v += j.resid[(size_t)rr * N + col];
                    if (j.Cf) j.Cf[(size_t)rr * N + col] = v;
                    if (j.Cb) j.Cb[(size_t)rr * N + col] = f2bf(v);
                }
            }
        }
    }
}

// ---------------------------------------------------------------------------
// Prep: convert all weights + knowledge + x to bf16 (one pass), copy x -> h.
// Everything processed as float4 -> ushort4 (all segment sizes % 4 == 0).
// ---------------------------------------------------------------------------
struct PrepArgs {
    const float *Wq, *Wk, *Wvs, *Wvo, *Wo, *Wkn, *w1, *w2, *know, *x;
    ushort *wqkvv, *wo, *wkn, *w1b, *w2b, *knowb, *hb;
    float *h;
};
#define P4_WQKVV 1048576
#define P4_B1 (P4_WQKVV + 262144)          // wo
#define P4_B2 (P4_B1 + 262144)             // wkn
#define P4_B3 (P4_B2 + 1048576)            // w1
#define P4_B4 (P4_B3 + 1048576)            // w2
#define P4_B5 (P4_B4 + 128000)             // knowledge
#define P4_TOT (P4_B5 + 65536)             // x

__global__ __launch_bounds__(256) void prep_kernel(PrepArgs p)
{
    const int i = blockIdx.x * 256 + threadIdx.x;
    if (i >= P4_TOT) return;
    const float4* src;
    ushort4* dst;
    bool isx = false;
    if (i < P4_WQKVV) {           // [L][4*512][512]: per-layer concat Wq|Wk|Wvs|Wvo
        const int l = i >> 18, r = i & 262143, q = r >> 16;
        const float* s = (q == 0 ? p.Wq : q == 1 ? p.Wk : q == 2 ? p.Wvs : p.Wvo);
        src = (const float4*)s + l * 65536 + (r & 65535);
        dst = (ushort4*)p.wqkvv + i;
    } else if (i < P4_B1) {
        const int k = i - P4_WQKVV;
        src = (const float4*)p.Wo + k; dst = (ushort4*)p.wo + k;
    } else if (i < P4_B2) {
        const int k = i - P4_B1;
        src = (const float4*)p.Wkn + k; dst = (ushort4*)p.wkn + k;
    } else if (i < P4_B3) {
        const int k = i - P4_B2;
        src = (const float4*)p.w1 + k; dst = (ushort4*)p.w1b + k;
    } else if (i < P4_B4) {
        const int k = i - P4_B3;
        src = (const float4*)p.w2 + k; dst = (ushort4*)p.w2b + k;
    } else if (i < P4_B5) {
        const int k = i - P4_B4;
        src = (const float4*)p.know + k; dst = (ushort4*)p.knowb + k;
    } else {
        const int k = i - P4_B5;
        src = (const float4*)p.x + k; dst = (ushort4*)p.hb + k;
        ((float4*)p.h)[k] = *src;
        isx = true;
    }
    float4 v = *src;
    ushort4 o; o.x = f2bf(v.x); o.y = f2bf(v.y); o.z = f2bf(v.z); o.w = f2bf(v.w);
    *dst = o;
    (void)isx;
}

// ---------------------------------------------------------------------------
// LayerNorm rows of 512 (fp32 in), writes fp32 Yf and bf16 Yb.
// ---------------------------------------------------------------------------
__global__ __launch_bounds__(256) void ln_kernel(
    const float* __restrict__ X, const float* __restrict__ g,
    const float* __restrict__ bt, float* __restrict__ Yf,
    ushort* __restrict__ Yb, int rows)
{
    const int w = threadIdx.x >> 6, lane = threadIdx.x & 63;
    const int row = blockIdx.x * 4 + w;
    if (row >= rows) return;
    const float* x = X + (size_t)row * EE;
    float4 v0 = ((const float4*)x)[lane];
    float4 v1 = ((const float4*)x)[lane + 64];
    float s  = v0.x + v0.y + v0.z + v0.w + v1.x + v1.y + v1.z + v1.w;
    float q2 = v0.x*v0.x + v0.y*v0.y + v0.z*v0.z + v0.w*v0.w
             + v1.x*v1.x + v1.y*v1.y + v1.z*v1.z + v1.w*v1.w;
#pragma unroll
    for (int o = 32; o; o >>= 1) { s += __shfl_xor(s, o); q2 += __shfl_xor(q2, o); }
    const float mean = s * (1.f / EE);
    const float var  = q2 * (1.f / EE) - mean * mean;
    const float rstd = rsqrtf(var + 1e-5f);
    float4 g0 = ((const float4*)g)[lane],  g1 = ((const float4*)g)[lane + 64];
    float4 b0 = ((const float4*)bt)[lane], b1 = ((const float4*)bt)[lane + 64];
    float4 o0, o1;
    o0.x = (v0.x - mean) * rstd * g0.x + b0.x;
    o0.y = (v0.y - mean) * rstd * g0.y + b0.y;
    o0.z = (v0.z - mean) * rstd * g0.z + b0.z;
    o0.w = (v0.w - mean) * rstd * g0.w + b0.w;
    o1.x = (v1.x - mean) * rstd * g1.x + b1.x;
    o1.y = (v1.y - mean) * rstd * g1.y + b1.y;
    o1.z = (v1.z - mean) * rstd * g1.z + b1.z;
    o1.w = (v1.w - mean) * rstd * g1.w + b1.w;
    float* y = Yf + (size_t)row * EE;
    ((float4*)y)[lane] = o0;
    ((float4*)y)[lane + 64] = o1;
    ushort* yb = Yb + (size_t)row * EE;
    ushort4 p0, p1;
    p0.x = f2bf(o0.x); p0.y = f2bf(o0.y); p0.z = f2bf(o0.z); p0.w = f2bf(o0.w);
    p1.x = f2bf(o1.x); p1.y = f2bf(o1.y); p1.z = f2bf(o1.z); p1.w = f2bf(o1.w);
    ((ushort4*)yb)[lane] = p0;
    ((ushort4*)yb)[lane + 64] = p1;
}

// ---------------------------------------------------------------------------
// Fused attention, bf16 activations. qkvv = [512][2048] bf16 (q|k|vs|vo),
// kproj = [1024][512] bf16. Output asum bf16 [512][512]. fp32 internal math.
// ---------------------------------------------------------------------------
__global__ __launch_bounds__(256) void attn_kernel(
    const ushort* __restrict__ qkvv, const ushort* __restrict__ kproj,
    const int* __restrict__ know_adj, const int* __restrict__ pos_mask,
    const float* __restrict__ pe_k, const float* __restrict__ pe_v,
    const int* __restrict__ adj, const int* __restrict__ s_mask,
    const int* __restrict__ o_mask, ushort* __restrict__ asum)
{
    const int blk = blockIdx.x;
    const int b = blk >> 7, i = blk & 127;
    const int t = threadIdx.x;

    __shared__ float q_s[EE];
    __shared__ float sc[NH][SS];
    __shared__ float qpe[NH][11];
    __shared__ float ap[NH][11];
    __shared__ float ws_s[SS], wo_s[SS];
    __shared__ int   pos_s[SS], n_s[SS], adj_s[SS];

    // phase 0: q row (bf16 -> f32 LDS) + per-j metadata
    if (t < 64) {
        uint4 v = *(const uint4*)(qkvv + (size_t)(b * SS + i) * LDQ + t * 8);
        float* qd = q_s + t * 8;
        qd[0] = bflo(v.x); qd[1] = bfhi(v.x); qd[2] = bflo(v.y); qd[3] = bfhi(v.y);
        qd[4] = bflo(v.z); qd[5] = bfhi(v.z); qd[6] = bflo(v.w); qd[7] = bfhi(v.w);
    } else if (t >= 128) {
        const int jj = t - 128;
        const size_t off = ((size_t)(b * SS + i)) * SS + jj;
        n_s[jj]   = know_adj[off];
        adj_s[jj] = adj[off];
        ws_s[jj]  = (float)s_mask[off];
        wo_s[jj]  = (float)o_mask[off];
        int p = pos_mask[i * SS + jj];
        pos_s[jj] = p > 10 ? 10 : (p < 0 ? 0 : p);
    }
    __syncthreads();

    // phase 1: qpe[h][p] = q_h . pe_k[p]; zero ap
    if (t < NH * 11) {
        const int h = t / 11, p = t % 11;
        const float* pk = pe_k + p * HD;
        const float* qh = q_s + h * HD;
        float a = 0.f;
#pragma unroll
        for (int d = 0; d < HD; ++d) a += qh[d] * pk[d];
        qpe[h][p] = a;
        ap[h][p] = 0.f;
    }
    __syncthreads();

    // phase 2: scores. thread -> (j = t>>1, half s = t&1 -> 4 heads)
    {
        const int jj = t >> 1, s = t & 1;
        const uint4* kp4 = (const uint4*)(kproj + (size_t)n_s[jj] * EE + s * 256);
        const uint4* kr4 = (const uint4*)(qkvv + (size_t)(b * SS + jj) * LDQ + EE + s * 256);
        const float amask = adj_s[jj] ? 0.f : 1e30f;
        const int p = pos_s[jj];
#pragma unroll
        for (int h4 = 0; h4 < 4; ++h4) {
            const int h = s * 4 + h4;
            const float* qh = q_s + h * HD;
            float a = 0.f;
#pragma unroll
            for (int dv = 0; dv < 8; ++dv) {
                uint4 kv = kr4[h4 * 8 + dv];
                uint4 pv = kp4[h4 * 8 + dv];
                const float* q8 = qh + dv * 8;
                a += q8[0] * (bflo(kv.x) + bflo(pv.x));
                a += q8[1] * (bfhi(kv.x) + bfhi(pv.x));
                a += q8[2] * (bflo(kv.y) + bflo(pv.y));
                a += q8[3] * (bfhi(kv.y) + bfhi(pv.y));
                a += q8[4] * (bflo(kv.z) + bflo(pv.z));
                a += q8[5] * (bfhi(kv.z) + bfhi(pv.z));
                a += q8[6] * (bflo(kv.w) + bflo(pv.w));
                a += q8[7] * (bfhi(kv.w) + bfhi(pv.w));
            }
            sc[h][jj] = (a + qpe[h][p]) * 0.125f - amask;
        }
    }
    __syncthreads();

    // phase 3: softmax per head + ap accumulation
    {
        const int w = t >> 6, lane = t & 63;
#pragma unroll
        for (int hh = 0; hh < 2; ++hh) {
            const int h = w * 2 + hh;
            float v0 = sc[h][lane], v1 = sc[h][lane + 64];
            float m = fmaxf(v0, v1);
#pragma unroll
            for (int o = 32; o; o >>= 1) m = fmaxf(m, __shfl_xor(m, o));
            float e0 = __expf(v0 - m), e1 = __expf(v1 - m);
            float ssum = e0 + e1;
#pragma unroll
            for (int o = 32; o; o >>= 1) ssum += __shfl_xor(ssum, o);
            const float inv = 1.f / ssum;
            e0 *= inv; e1 *= inv;
            sc[h][lane] = e0; sc[h][lane + 64] = e1;
            atomicAdd(&ap[h][pos_s[lane]], e0);
            atomicAdd(&ap[h][pos_s[lane + 64]], e1);
        }
    }
    __syncthreads();

    // phase 4: out[h][d]; thread -> (h0 = t>>6, d = t&63) and h0+4
    {
        const int h0 = t >> 6, d = t & 63, h1 = h0 + 4;
        float acc0 = 0.f, acc1 = 0.f;
        const ushort* vbase = qkvv + (size_t)b * SS * LDQ + 1024;  // vs block
        for (int jj = 0; jj < SS; ++jj) {
            const float a0 = sc[h0][jj], a1 = sc[h1][jj];
            const float wsj = ws_s[jj], woj = wo_s[jj];
            const ushort* r = vbase + (size_t)jj * LDQ;
            const float vs0 = bfu(r[h0 * HD + d]);
            const float vo0 = bfu(r[512 + h0 * HD + d]);
            const float vs1 = bfu(r[h1 * HD + d]);
            const float vo1 = bfu(r[512 + h1 * HD + d]);
            acc0 += a0 * (wsj * vs0 + woj * vo0);
            acc1 += a1 * (wsj * vs1 + woj * vo1);
        }
#pragma unroll
        for (int p = 0; p < 11; ++p) {
            acc0 += ap[h0][p] * pe_v[p * HD + d];
            acc1 += ap[h1][p] * pe_v[p * HD + d];
        }
        const size_t ob = (size_t)(b * SS + i) * EE;
        asum[ob + h0 * HD + d] = f2bf(acc0);
        asum[ob + h1 * HD + d] = f2bf(acc1);
    }
}

// ---------------------------------------------------------------------------
extern "C" void kernel_launch(void* const* d_in, const int* in_sizes, int n_in,
                              void* d_out, int out_size, void* d_ws, size_t ws_size,
                              hipStream_t stream)
{
    const float* x         = (const float*)d_in[0];
    const int*   adj       = (const int*)d_in[1];
    const int*   s_mask    = (const int*)d_in[2];
    const int*   o_mask    = (const int*)d_in[3];
    const float* knowledge = (const float*)d_in[4];
    const int*   know_adj  = (const int*)d_in[5];
    const int*   pos_mask  = (const int*)d_in[6];
    const float* pe_k      = (const float*)d_in[7];
    const float* pe_v      = (const float*)d_in[8];
    const float* Wq        = (const float*)d_in[9];
    const float* Wk        = (const float*)d_in[10];
    const float* Wvs       = (const float*)d_in[11];
    const float* Wvo       = (const float*)d_in[12];
    const float* Wo        = (const float*)d_in[13];
    const float* Wkn       = (const float*)d_in[14];
    const float* ln1_g     = (const float*)d_in[15];
    const float* ln1_b     = (const float*)d_in[16];
    const float* w1        = (const float*)d_in[17];
    const float* b1        = (const float*)d_in[18];
    const float* w2        = (const float*)d_in[19];
    const float* b2        = (const float*)d_in[20];
    const float* ln2_g     = (const float*)d_in[21];
    const float* ln2_b     = (const float*)d_in[22];

    const int NTOK = BB * SS;                 // 512
    const size_t NTE = (size_t)NTOK * EE;     // 262144

    // workspace layout
    float*  h      = (float*)d_ws;            // 1 MB
    float*  xt     = h + NTE;                 // 1 MB
    ushort* hb     = (ushort*)(xt + NTE);     // 512 KB
    ushort* qkvv   = hb + NTE;                // 2 MB
    ushort* kprojb = qkvv + (size_t)NTOK * LDQ;      // 1 MB (1024 rows)
    ushort* asumb  = kprojb + 1024 * EE;      // 512 KB
    ushort* ffnb   = asumb + NTE;             // 2 MB
    ushort* wqkvv  = ffnb + (size_t)NTOK * FFD;      // 8 MB
    ushort* wob    = wqkvv + (size_t)NL * 4 * EE * EE; // 2 MB
    ushort* wknb   = wob + (size_t)NL * EE * EE;       // 2 MB
    ushort* w1b    = wknb + (size_t)NL * EE * EE;      // 8 MB
    ushort* w2b    = w1b + (size_t)NL * FFD * EE;      // 8 MB
    ushort* knowb  = w2b + (size_t)NL * EE * FFD;      // 1 MB

    PrepArgs pa;
    pa.Wq = Wq; pa.Wk = Wk; pa.Wvs = Wvs; pa.Wvo = Wvo; pa.Wo = Wo; pa.Wkn = Wkn;
    pa.w1 = w1; pa.w2 = w2; pa.know = knowledge; pa.x = x;
    pa.wqkvv = wqkvv; pa.wo = wob; pa.wkn = wknb; pa.w1b = w1b; pa.w2b = w2b;
    pa.knowb = knowb; pa.hb = hb; pa.h = h;
    prep_kernel<<<dim3((P4_TOT + 255) / 256), dim3(256), 0, stream>>>(pa);

    const dim3 blk(256);
    for (int l = 0; l < NL; ++l) {
        GemmJob jq{};   // QKVV concat: [512,2048] = h @ Wqkvv_l^T
        jq.A = hb; jq.B = wqkvv + (size_t)l * 4 * EE * EE;
        jq.Cb = qkvv; jq.M = NTOK; jq.N = 4 * EE; jq.K = EE;
        jq.nbx = 32; jq.base = 0;
        GemmJob jk{};   // kproj: [1000,512] = knowledge @ Wkn_l^T
        jk.A = knowb; jk.B = wknb + (size_t)l * EE * EE;
        jk.Cb = kprojb; jk.M = 1000; jk.N = EE; jk.K = EE;
        jk.nbx = 8; jk.base = 256;
        gemm_bf16<64><<<dim3(256 + 128), blk, 0, stream>>>(jq, jk, 2);

        attn_kernel<<<dim3(NTOK), blk, 0, stream>>>(qkvv, kprojb, know_adj, pos_mask,
                                                    pe_k, pe_v, adj, s_mask, o_mask, asumb);

        GemmJob jo{};   // Wo: xt = asum @ Wo_l^T + h
        jo.A = asumb; jo.B = wob + (size_t)l * EE * EE;
        jo.Cf = xt; jo.resid = h; jo.M = NTOK; jo.N = EE; jo.K = EE;
        jo.nbx = 8; jo.base = 0;
        gemm_bf16<32><<<dim3(128), blk, 0, stream>>>(jo, jo, 1);

        ln_kernel<<<dim3(128), blk, 0, stream>>>(xt, ln1_g + l * EE, ln1_b + l * EE,
                                                 h, hb, NTOK);

        GemmJob jf1{};  // FFN1: relu(h @ w1_l^T + b1) -> bf16
        jf1.A = hb; jf1.B = w1b + (size_t)l * FFD * EE;
        jf1.Cb = ffnb; jf1.bias = b1 + (size_t)l * FFD; jf1.flags = 3;
        jf1.M = NTOK; jf1.N = FFD; jf1.K = EE; jf1.nbx = 32; jf1.base = 0;
        gemm_bf16<64><<<dim3(256), blk, 0, stream>>>(jf1, jf1, 1);

        GemmJob jf2{};  // FFN2: xt = ffn @ w2_l^T + b2 + h
        jf2.A = ffnb; jf2.B = w2b + (size_t)l * EE * FFD;
        jf2.Cf = xt; jf2.bias = b2 + (size_t)l * EE; jf2.resid = h; jf2.flags = 1;
        jf2.M = NTOK; jf2.N = EE; jf2.K = FFD; jf2.nbx = 8; jf2.base = 0;
        gemm_bf16<32><<<dim3(128), blk, 0, stream>>>(jf2, jf2, 1);

        float* lnout = (l == NL - 1) ? (float*)d_out : h;
        ln_kernel<<<dim3(128), blk, 0, stream>>>(xt, ln2_g + l * EE, ln2_b + l * EE,
                                                 lnout, hb, NTOK);
    }
}

// Round 4
// 554.551 us; speedup vs baseline: 2.4571x; 1.3458x over previous
//
#include <hip/hip_runtime.h>

#define EE 512
#define SS 128
#define BB 4
#define NH 8
#define HD 64
#define FFD 2048
#define NL 4
#define LDQ 2048   // qkvv concat leading dim

typedef short bf16x8 __attribute__((ext_vector_type(8)));
typedef float f32x4 __attribute__((ext_vector_type(4)));

__device__ __forceinline__ ushort f2bf(float f) {
    uint u = __float_as_uint(f);
    return (ushort)((u + 0x7fffu + ((u >> 16) & 1u)) >> 16);
}
__device__ __forceinline__ float bflo(uint u) { return __uint_as_float(u << 16); }
__device__ __forceinline__ float bfhi(uint u) { return __uint_as_float(u & 0xffff0000u); }

// async 16B global->LDS. LDS dest = wave-uniform base + lane*16 (HW rule).
__device__ __forceinline__ void gll16(const ushort* g, ushort* l) {
    __builtin_amdgcn_global_load_lds(
        (const __attribute__((address_space(1))) void*)g,
        (__attribute__((address_space(3))) void*)l, 16, 0, 0);
}

// ---------------------------------------------------------------------------
// bf16 MFMA GEMM, 2-phase double-buffered global_load_lds pipeline.
// C[M,N] = A[M,K] @ B[N,K]^T.  BM=32, BN=64, BK=64, 256 thr / 4 waves.
// LDS layout K-chunk-major: As[buf][chunk c=0..7][row]: 16B per (c,row).
//   A chunk = 32 rows*16B = 512B; B chunk = 64 rows*16B = 1KB.
// Wave staging: B chunks 2w,2w+1 (row=lane); A chunks 2w..2w+1
//   (row=lane&31, chunk=2w+(lane>>5)), one gll16 per chunk-pair.
// Fragment reads are 16 consecutive 16B slots per quad -> conflict-free.
// flags: bit0=+bias[col], bit1=relu. resid f32 optional. Cf f32 / Cb bf16 out.
// Two jobs per launch (block ranges) to batch small GEMMs.
// ---------------------------------------------------------------------------
struct GemmJob {
    const ushort* A; const ushort* B;
    float* Cf; ushort* Cb;
    const float* bias; const float* resid;
    int M, N, K, flags, nbx, base;
};

__global__ __launch_bounds__(256) void gemm_bf16(GemmJob j0, GemmJob j1, int njobs)
{
    constexpr int BM = 32;
    __shared__ ushort As[2][8 * BM * 8];   // 2 x 4KB
    __shared__ ushort Bs[2][8 * 64 * 8];   // 2 x 8KB
    GemmJob j = (njobs > 1 && (int)blockIdx.x >= j1.base) ? j1 : j0;
    const int bid = (int)blockIdx.x - j.base;
    const int by = bid / j.nbx, bx = bid % j.nbx;
    const int rowBase = by * BM, colBase = bx * 64;
    const int t = threadIdx.x, lane = t & 63, wid = t >> 6;
    // wave tile: WM=1, WN=4, NREP=1: wave wc covers cols wc*16..+15, rows 0..31
    const int wc = wid;
    const int Kd = j.K, Md = j.M, Nd = j.N;

    // precomputed staging addresses (k0 added per step)
    const ushort* Bg = j.B + (size_t)(colBase + lane) * Kd;       // per-lane row
    int gr = rowBase + (lane & 31); if (gr >= Md) gr = Md - 1;
    const ushort* Ag = j.A + (size_t)gr * Kd + (2 * wid + (lane >> 5)) * 8;

    f32x4 acc[2];
#pragma unroll
    for (int m = 0; m < 2; ++m)
#pragma unroll
        for (int r = 0; r < 4; ++r) acc[m][r] = 0.f;

    auto STAGE = [&](int bf, int k0) {
        gll16(Bg + k0 + (2 * wid) * 8,     &Bs[bf][(2 * wid) * 512]);
        gll16(Bg + k0 + (2 * wid + 1) * 8, &Bs[bf][(2 * wid + 1) * 512]);
        gll16(Ag + k0,                     &As[bf][(2 * wid) * 256]);
    };
    auto COMPUTE = [&](int bf) {
#pragma unroll
        for (int kc = 0; kc < 2; ++kc) {
            const int c16 = kc * 4 + (lane >> 4);
            bf16x8 af[2], bfg;
#pragma unroll
            for (int m = 0; m < 2; ++m) {
                const int row = m * 16 + (lane & 15);
                af[m] = *(const bf16x8*)&As[bf][c16 * 256 + row * 8];
            }
            {
                const int rowb = wc * 16 + (lane & 15);
                bfg = *(const bf16x8*)&Bs[bf][c16 * 512 + rowb * 8];
            }
#pragma unroll
            for (int m = 0; m < 2; ++m)
                acc[m] = __builtin_amdgcn_mfma_f32_16x16x32_bf16(af[m], bfg, acc[m], 0, 0, 0);
        }
    };

    const int nt = Kd >> 6;
    STAGE(0, 0);
    __syncthreads();            // drains vmcnt: buf0 ready
    int cur = 0;
    for (int tt = 0; tt < nt - 1; ++tt) {
        STAGE(cur ^ 1, (tt + 1) << 6);   // async: in flight during compute
        COMPUTE(cur);
        __syncthreads();                  // drain staging + all waves done reading
        cur ^= 1;
    }
    COMPUTE(cur);

    // epilogue: C/D layout col=lane&15, row=(lane>>4)*4+reg  [m89-verified]
    const int cl = lane & 15, rh = lane >> 4;
#pragma unroll
    for (int m = 0; m < 2; ++m) {
        const int col = colBase + wc * 16 + cl;
        const int row0 = rowBase + m * 16 + rh * 4;
#pragma unroll
        for (int r = 0; r < 4; ++r) {
            const int rr = row0 + r;
            if (rr < Md) {
                float v = acc[m][r];
                if (j.flags & 1) v += j.bias[col];
                if (j.flags & 2) v = fmaxf(v, 0.f);
                if (j.resid) v += j.resid[(size_t)rr * Nd + col];
                if (j.Cf) j.Cf[(size_t)rr * Nd + col] = v;
                if (j.Cb) j.Cb[(size_t)rr * Nd + col] = f2bf(v);
            }
        }
    }
}

// ---------------------------------------------------------------------------
// Prep: convert all weights + knowledge + x to bf16 (one pass), copy x -> h.
// ---------------------------------------------------------------------------
struct PrepArgs {
    const float *Wq, *Wk, *Wvs, *Wvo, *Wo, *Wkn, *w1, *w2, *know, *x;
    ushort *wqkvv, *wo, *wkn, *w1b, *w2b, *knowb, *hb;
    float *h;
};
#define P4_WQKVV 1048576
#define P4_B1 (P4_WQKVV + 262144)          // wo
#define P4_B2 (P4_B1 + 262144)             // wkn
#define P4_B3 (P4_B2 + 1048576)            // w1
#define P4_B4 (P4_B3 + 1048576)            // w2
#define P4_B5 (P4_B4 + 128000)             // knowledge
#define P4_TOT (P4_B5 + 65536)             // x

__global__ __launch_bounds__(256) void prep_kernel(PrepArgs p)
{
    const int i = blockIdx.x * 256 + threadIdx.x;
    if (i >= P4_TOT) return;
    const float4* src;
    ushort4* dst;
    if (i < P4_WQKVV) {           // [L][4*512][512]: per-layer concat Wq|Wk|Wvs|Wvo
        const int l = i >> 18, r = i & 262143, q = r >> 16;
        const float* s = (q == 0 ? p.Wq : q == 1 ? p.Wk : q == 2 ? p.Wvs : p.Wvo);
        src = (const float4*)s + l * 65536 + (r & 65535);
        dst = (ushort4*)p.wqkvv + i;
    } else if (i < P4_B1) {
        const int k = i - P4_WQKVV;
        src = (const float4*)p.Wo + k; dst = (ushort4*)p.wo + k;
    } else if (i < P4_B2) {
        const int k = i - P4_B1;
        src = (const float4*)p.Wkn + k; dst = (ushort4*)p.wkn + k;
    } else if (i < P4_B3) {
        const int k = i - P4_B2;
        src = (const float4*)p.w1 + k; dst = (ushort4*)p.w1b + k;
    } else if (i < P4_B4) {
        const int k = i - P4_B3;
        src = (const float4*)p.w2 + k; dst = (ushort4*)p.w2b + k;
    } else if (i < P4_B5) {
        const int k = i - P4_B4;
        src = (const float4*)p.know + k; dst = (ushort4*)p.knowb + k;
    } else {
        const int k = i - P4_B5;
        src = (const float4*)p.x + k; dst = (ushort4*)p.hb + k;
        ((float4*)p.h)[k] = *src;
    }
    float4 v = *src;
    ushort4 o; o.x = f2bf(v.x); o.y = f2bf(v.y); o.z = f2bf(v.z); o.w = f2bf(v.w);
    *dst = o;
}

// ---------------------------------------------------------------------------
// LayerNorm rows of 512 (fp32 in), writes fp32 Yf and bf16 Yb.
// ---------------------------------------------------------------------------
__global__ __launch_bounds__(256) void ln_kernel(
    const float* __restrict__ X, const float* __restrict__ g,
    const float* __restrict__ bt, float* __restrict__ Yf,
    ushort* __restrict__ Yb, int rows)
{
    const int w = threadIdx.x >> 6, lane = threadIdx.x & 63;
    const int row = blockIdx.x * 4 + w;
    if (row >= rows) return;
    const float* x = X + (size_t)row * EE;
    float4 v0 = ((const float4*)x)[lane];
    float4 v1 = ((const float4*)x)[lane + 64];
    float s  = v0.x + v0.y + v0.z + v0.w + v1.x + v1.y + v1.z + v1.w;
    float q2 = v0.x*v0.x + v0.y*v0.y + v0.z*v0.z + v0.w*v0.w
             + v1.x*v1.x + v1.y*v1.y + v1.z*v1.z + v1.w*v1.w;
#pragma unroll
    for (int o = 32; o; o >>= 1) { s += __shfl_xor(s, o); q2 += __shfl_xor(q2, o); }
    const float mean = s * (1.f / EE);
    const float var  = q2 * (1.f / EE) - mean * mean;
    const float rstd = rsqrtf(var + 1e-5f);
    float4 g0 = ((const float4*)g)[lane],  g1 = ((const float4*)g)[lane + 64];
    float4 b0 = ((const float4*)bt)[lane], b1 = ((const float4*)bt)[lane + 64];
    float4 o0, o1;
    o0.x = (v0.x - mean) * rstd * g0.x + b0.x;
    o0.y = (v0.y - mean) * rstd * g0.y + b0.y;
    o0.z = (v0.z - mean) * rstd * g0.z + b0.z;
    o0.w = (v0.w - mean) * rstd * g0.w + b0.w;
    o1.x = (v1.x - mean) * rstd * g1.x + b1.x;
    o1.y = (v1.y - mean) * rstd * g1.y + b1.y;
    o1.z = (v1.z - mean) * rstd * g1.z + b1.z;
    o1.w = (v1.w - mean) * rstd * g1.w + b1.w;
    float* y = Yf + (size_t)row * EE;
    ((float4*)y)[lane] = o0;
    ((float4*)y)[lane + 64] = o1;
    ushort* yb = Yb + (size_t)row * EE;
    ushort4 p0, p1;
    p0.x = f2bf(o0.x); p0.y = f2bf(o0.y); p0.z = f2bf(o0.z); p0.w = f2bf(o0.w);
    p1.x = f2bf(o1.x); p1.y = f2bf(o1.y); p1.z = f2bf(o1.z); p1.w = f2bf(o1.w);
    ((ushort4*)yb)[lane] = p0;
    ((ushort4*)yb)[lane + 64] = p1;
}

// ---------------------------------------------------------------------------
// Fused attention, bf16 activations. qkvv = [512][2048] bf16 (q|k|vs|vo),
// kproj = [1024][512] bf16. Output asum bf16 [512][512]. fp32 internal math.
// ---------------------------------------------------------------------------
__global__ __launch_bounds__(256) void attn_kernel(
    const ushort* __restrict__ qkvv, const ushort* __restrict__ kproj,
    const int* __restrict__ know_adj, const int* __restrict__ pos_mask,
    const float* __restrict__ pe_k, const float* __restrict__ pe_v,
    const int* __restrict__ adj, const int* __restrict__ s_mask,
    const int* __restrict__ o_mask, ushort* __restrict__ asum)
{
    const int blk = blockIdx.x;
    const int b = blk >> 7, i = blk & 127;
    const int t = threadIdx.x;

    __shared__ float q_s[EE];
    __shared__ float sc[NH][SS];
    __shared__ float qpe[NH][11];
    __shared__ float ap[NH][11];
    __shared__ float ws_s[SS], wo_s[SS];
    __shared__ int   pos_s[SS], n_s[SS], adj_s[SS];

    // phase 0: q row (bf16 -> f32 LDS) + per-j metadata
    if (t < 64) {
        uint4 v = *(const uint4*)(qkvv + (size_t)(b * SS + i) * LDQ + t * 8);
        float* qd = q_s + t * 8;
        qd[0] = bflo(v.x); qd[1] = bfhi(v.x); qd[2] = bflo(v.y); qd[3] = bfhi(v.y);
        qd[4] = bflo(v.z); qd[5] = bfhi(v.z); qd[6] = bflo(v.w); qd[7] = bfhi(v.w);
    } else if (t >= 128) {
        const int jj = t - 128;
        const size_t off = ((size_t)(b * SS + i)) * SS + jj;
        n_s[jj]   = know_adj[off];
        adj_s[jj] = adj[off];
        ws_s[jj]  = (float)s_mask[off];
        wo_s[jj]  = (float)o_mask[off];
        int p = pos_mask[i * SS + jj];
        pos_s[jj] = p > 10 ? 10 : (p < 0 ? 0 : p);
    }
    __syncthreads();

    // phase 1: qpe[h][p] = q_h . pe_k[p]; zero ap
    if (t < NH * 11) {
        const int h = t / 11, p = t % 11;
        const float* pk = pe_k + p * HD;
        const float* qh = q_s + h * HD;
        float a = 0.f;
#pragma unroll
        for (int d = 0; d < HD; ++d) a += qh[d] * pk[d];
        qpe[h][p] = a;
        ap[h][p] = 0.f;
    }
    __syncthreads();

    // phase 2: scores. thread -> (j = t>>1, half s = t&1 -> 4 heads)
    {
        const int jj = t >> 1, s = t & 1;
        const uint4* kp4 = (const uint4*)(kproj + (size_t)n_s[jj] * EE + s * 256);
        const uint4* kr4 = (const uint4*)(qkvv + (size_t)(b * SS + jj) * LDQ + EE + s * 256);
        const float amask = adj_s[jj] ? 0.f : 1e30f;
        const int p = pos_s[jj];
#pragma unroll
        for (int h4 = 0; h4 < 4; ++h4) {
            const int h = s * 4 + h4;
            const float* qh = q_s + h * HD;
            float a = 0.f;
#pragma unroll
            for (int dv = 0; dv < 8; ++dv) {
                uint4 kv = kr4[h4 * 8 + dv];
                uint4 pv = kp4[h4 * 8 + dv];
                const float* q8 = qh + dv * 8;
                a += q8[0] * (bflo(kv.x) + bflo(pv.x));
                a += q8[1] * (bfhi(kv.x) + bfhi(pv.x));
                a += q8[2] * (bflo(kv.y) + bflo(pv.y));
                a += q8[3] * (bfhi(kv.y) + bfhi(pv.y));
                a += q8[4] * (bflo(kv.z) + bflo(pv.z));
                a += q8[5] * (bfhi(kv.z) + bfhi(pv.z));
                a += q8[6] * (bflo(kv.w) + bflo(pv.w));
                a += q8[7] * (bfhi(kv.w) + bfhi(pv.w));
            }
            sc[h][jj] = (a + qpe[h][p]) * 0.125f - amask;
        }
    }
    __syncthreads();

    // phase 3: softmax per head + ap accumulation
    {
        const int w = t >> 6, lane = t & 63;
#pragma unroll
        for (int hh = 0; hh < 2; ++hh) {
            const int h = w * 2 + hh;
            float v0 = sc[h][lane], v1 = sc[h][lane + 64];
            float m = fmaxf(v0, v1);
#pragma unroll
            for (int o = 32; o; o >>= 1) m = fmaxf(m, __shfl_xor(m, o));
            float e0 = __expf(v0 - m), e1 = __expf(v1 - m);
            float ssum = e0 + e1;
#pragma unroll
            for (int o = 32; o; o >>= 1) ssum += __shfl_xor(ssum, o);
            const float inv = 1.f / ssum;
            e0 *= inv; e1 *= inv;
            sc[h][lane] = e0; sc[h][lane + 64] = e1;
            atomicAdd(&ap[h][pos_s[lane]], e0);
            atomicAdd(&ap[h][pos_s[lane + 64]], e1);
        }
    }
    __syncthreads();

    // phase 4: thread t -> head h = t>>5, d pair d0 = (t&31)*2. Coalesced uint loads.
    {
        const int h = t >> 5, d0 = (t & 31) * 2;
        float a0 = 0.f, a1 = 0.f;
        const ushort* vbase = qkvv + (size_t)b * SS * LDQ + 1024 + h * HD + d0;
        for (int jj = 0; jj < SS; ++jj) {
            const float aw = sc[h][jj];
            const float wsj = ws_s[jj], woj = wo_s[jj];
            const ushort* r = vbase + (size_t)jj * LDQ;
            const uint vsp = *(const uint*)r;          // vs pair (d0, d0+1)
            const uint vop = *(const uint*)(r + 512);  // vo pair
            a0 += aw * (wsj * bflo(vsp) + woj * bflo(vop));
            a1 += aw * (wsj * bfhi(vsp) + woj * bfhi(vop));
        }
#pragma unroll
        for (int p = 0; p < 11; ++p) {
            const float apv = ap[h][p];
            a0 += apv * pe_v[p * HD + d0];
            a1 += apv * pe_v[p * HD + d0 + 1];
        }
        const uint o = (uint)f2bf(a0) | ((uint)f2bf(a1) << 16);
        *(uint*)(asum + (size_t)(b * SS + i) * EE + h * HD + d0) = o;
    }
}

// ---------------------------------------------------------------------------
extern "C" void kernel_launch(void* const* d_in, const int* in_sizes, int n_in,
                              void* d_out, int out_size, void* d_ws, size_t ws_size,
                              hipStream_t stream)
{
    const float* x         = (const float*)d_in[0];
    const int*   adj       = (const int*)d_in[1];
    const int*   s_mask    = (const int*)d_in[2];
    const int*   o_mask    = (const int*)d_in[3];
    const float* knowledge = (const float*)d_in[4];
    const int*   know_adj  = (const int*)d_in[5];
    const int*   pos_mask  = (const int*)d_in[6];
    const float* pe_k      = (const float*)d_in[7];
    const float* pe_v      = (const float*)d_in[8];
    const float* Wq        = (const float*)d_in[9];
    const float* Wk        = (const float*)d_in[10];
    const float* Wvs       = (const float*)d_in[11];
    const float* Wvo       = (const float*)d_in[12];
    const float* Wo        = (const float*)d_in[13];
    const float* Wkn       = (const float*)d_in[14];
    const float* ln1_g     = (const float*)d_in[15];
    const float* ln1_b     = (const float*)d_in[16];
    const float* w1        = (const float*)d_in[17];
    const float* b1        = (const float*)d_in[18];
    const float* w2        = (const float*)d_in[19];
    const float* b2        = (const float*)d_in[20];
    const float* ln2_g     = (const float*)d_in[21];
    const float* ln2_b     = (const float*)d_in[22];

    const int NTOK = BB * SS;                 // 512
    const size_t NTE = (size_t)NTOK * EE;     // 262144

    // workspace layout
    float*  h      = (float*)d_ws;            // 1 MB
    float*  xt     = h + NTE;                 // 1 MB
    ushort* hb     = (ushort*)(xt + NTE);     // 512 KB
    ushort* qkvv   = hb + NTE;                // 2 MB
    ushort* kprojb = qkvv + (size_t)NTOK * LDQ;        // 1 MB (1024 rows)
    ushort* asumb  = kprojb + 1024 * EE;      // 512 KB
    ushort* ffnb   = asumb + NTE;             // 2 MB
    ushort* wqkvv  = ffnb + (size_t)NTOK * FFD;        // 8 MB
    ushort* wob    = wqkvv + (size_t)NL * 4 * EE * EE; // 2 MB
    ushort* wknb   = wob + (size_t)NL * EE * EE;       // 2 MB
    ushort* w1b    = wknb + (size_t)NL * EE * EE;      // 8 MB
    ushort* w2b    = w1b + (size_t)NL * FFD * EE;      // 8 MB
    ushort* knowb  = w2b + (size_t)NL * EE * FFD;      // 1 MB

    PrepArgs pa;
    pa.Wq = Wq; pa.Wk = Wk; pa.Wvs = Wvs; pa.Wvo = Wvo; pa.Wo = Wo; pa.Wkn = Wkn;
    pa.w1 = w1; pa.w2 = w2; pa.know = knowledge; pa.x = x;
    pa.wqkvv = wqkvv; pa.wo = wob; pa.wkn = wknb; pa.w1b = w1b; pa.w2b = w2b;
    pa.knowb = knowb; pa.hb = hb; pa.h = h;
    prep_kernel<<<dim3((P4_TOT + 255) / 256), dim3(256), 0, stream>>>(pa);

    const dim3 blk(256);
    for (int l = 0; l < NL; ++l) {
        GemmJob jq{};   // QKVV concat: [512,2048] = h @ Wqkvv_l^T   (512 blocks)
        jq.A = hb; jq.B = wqkvv + (size_t)l * 4 * EE * EE;
        jq.Cb = qkvv; jq.M = NTOK; jq.N = 4 * EE; jq.K = EE;
        jq.nbx = 32; jq.base = 0;
        GemmJob jk{};   // kproj: [1000,512] = knowledge @ Wkn_l^T   (256 blocks)
        jk.A = knowb; jk.B = wknb + (size_t)l * EE * EE;
        jk.Cb = kprojb; jk.M = 1000; jk.N = EE; jk.K = EE;
        jk.nbx = 8; jk.base = 512;
        gemm_bf16<<<dim3(768), blk, 0, stream>>>(jq, jk, 2);

        attn_kernel<<<dim3(NTOK), blk, 0, stream>>>(qkvv, kprojb, know_adj, pos_mask,
                                                    pe_k, pe_v, adj, s_mask, o_mask, asumb);

        GemmJob jo{};   // Wo: xt = asum @ Wo_l^T + h   (128 blocks)
        jo.A = asumb; jo.B = wob + (size_t)l * EE * EE;
        jo.Cf = xt; jo.resid = h; jo.M = NTOK; jo.N = EE; jo.K = EE;
        jo.nbx = 8; jo.base = 0;
        gemm_bf16<<<dim3(128), blk, 0, stream>>>(jo, jo, 1);

        ln_kernel<<<dim3(128), blk, 0, stream>>>(xt, ln1_g + l * EE, ln1_b + l * EE,
                                                 h, hb, NTOK);

        GemmJob jf1{};  // FFN1: relu(h @ w1_l^T + b1) -> bf16   (512 blocks)
        jf1.A = hb; jf1.B = w1b + (size_t)l * FFD * EE;
        jf1.Cb = ffnb; jf1.bias = b1 + (size_t)l * FFD; jf1.flags = 3;
        jf1.M = NTOK; jf1.N = FFD; jf1.K = EE; jf1.nbx = 32; jf1.base = 0;
        gemm_bf16<<<dim3(512), blk, 0, stream>>>(jf1, jf1, 1);

        GemmJob jf2{};  // FFN2: xt = ffn @ w2_l^T + b2 + h   (128 blocks, 32 K-steps)
        jf2.A = ffnb; jf2.B = w2b + (size_t)l * EE * FFD;
        jf2.Cf = xt; jf2.bias = b2 + (size_t)l * EE; jf2.resid = h; jf2.flags = 1;
        jf2.M = NTOK; jf2.N = EE; jf2.K = FFD; jf2.nbx = 8; jf2.base = 0;
        gemm_bf16<<<dim3(128), blk, 0, stream>>>(jf2, jf2, 1);

        float* lnout = (l == NL - 1) ? (float*)d_out : h;
        ln_kernel<<<dim3(128), blk, 0, stream>>>(xt, ln2_g + l * EE, ln2_b + l * EE,
                                                 lnout, hb, NTOK);
    }
}